// Round 3
// baseline (440.605 us; speedup 1.0000x reference)
//
#include <hip/hip_runtime.h>
#include <math.h>

typedef __attribute__((ext_vector_type(8))) short bf16x8;
typedef __attribute__((ext_vector_type(4))) short short4v;
typedef __attribute__((ext_vector_type(4))) float f32x4;

constexpr int S   = 2048;
constexpr int HID = 2048;
constexpr int NH  = 16;
constexpr int HD  = 128;
constexpr int HALF = 64;

#define SCORE_SCALE ((float)(0.06 * 0.06 * 0.08838834764831845))   // Q_ROT*K_ROT*INV_SQRT_HD
#define OSCALE      ((float)(((1.0 / 127.0) * 0.04) / 0.03))        // PROB*V_OUT/OUT_IN

__device__ __forceinline__ float bf2f(short u){
  union { float f; unsigned int i; } t;
  t.i = ((unsigned int)(unsigned short)u) << 16;
  return t.f;
}
__device__ __forceinline__ short f2bf(float f){
  union { float f; unsigned int i; } t; t.f = f;
  unsigned int r = t.i + 0x7fffu + ((t.i >> 16) & 1u);
  return (short)(r >> 16);
}
__device__ __forceinline__ float clip127(float r){
  return fminf(fmaxf(r, -127.0f), 127.0f);
}

// ---------------- prep: one dispatch converts x (quant) + 4 weights -----------
__global__ void cvt_all(const float* __restrict__ hid, const float* __restrict__ wq,
                        const float* __restrict__ wk, const float* __restrict__ wv,
                        const float* __restrict__ wo, short* __restrict__ xd,
                        short* __restrict__ qd, short* __restrict__ kd,
                        short* __restrict__ vd, short* __restrict__ od, int n){
  const float* srcs[5] = {hid, wq, wk, wv, wo};
  short* dsts[5] = {xd, qd, kd, vd, od};
  int which = blockIdx.y;
  const float* src = srcs[which];
  short* dst = dsts[which];
  int i = (blockIdx.x * blockDim.x + threadIdx.x) * 4;
  if (i >= n) return;
  float4 v = *(const float4*)(src + i);
  float x[4] = {v.x, v.y, v.z, v.w};
  short4v o;
#pragma unroll
  for (int j = 0; j < 4; ++j){
    float t = x[j];
    if (which == 0) t = clip127(rintf(t / 0.02f));
    o[j] = f2bf(t);
  }
  *(short4v*)(dst + i) = o;
}

// ---------------- GEMM: Y = A(MxK) * Bt(NxK)^T ---------------------------------
template<int MODE>
__global__ __launch_bounds__(256)
void gemm_bt(const short* __restrict__ A, const short* __restrict__ Bt,
             const float* __restrict__ bias, void* __restrict__ Y){
#pragma clang fp contract(off)
  constexpr int Kd = 2048, N = 2048;
  __shared__ __attribute__((aligned(16))) short As[128*32];
  __shared__ __attribute__((aligned(16))) short Bs[128*32];
  const int bm = blockIdx.x, bn = blockIdx.y;
  const int tid = threadIdx.x;
  const int wid = tid >> 6, lane = tid & 63;
  const int wm = wid >> 1, wn = wid & 1;
  const int col16 = lane & 15, g = lane >> 4;
  f32x4 acc[4][4] = {};
  const short* Ab = A + (size_t)(bm*128)*Kd;
  const short* Bb = Bt + (size_t)(bn*128)*Kd;
  for (int kt = 0; kt < Kd/32; ++kt){
#pragma unroll
    for (int i = 0; i < 2; ++i){
      int v = i*256 + tid;
      int row = v >> 2, cw = v & 3;
      int sw = (cw ^ ((row>>1)&3)) * 16;
      *(bf16x8*)((char*)As + row*64 + sw) = *(const bf16x8*)&Ab[(size_t)row*Kd + kt*32 + cw*8];
      *(bf16x8*)((char*)Bs + row*64 + sw) = *(const bf16x8*)&Bb[(size_t)row*Kd + kt*32 + cw*8];
    }
    __syncthreads();
    bf16x8 af[4], bfr[4];
#pragma unroll
    for (int i = 0; i < 4; ++i){
      int row = wm*64 + i*16 + col16;
      af[i] = *(const bf16x8*)((const char*)As + row*64 + ((g ^ ((row>>1)&3))*16));
    }
#pragma unroll
    for (int j = 0; j < 4; ++j){
      int row = wn*64 + j*16 + col16;
      bfr[j] = *(const bf16x8*)((const char*)Bs + row*64 + ((g ^ ((row>>1)&3))*16));
    }
#pragma unroll
    for (int i = 0; i < 4; ++i)
#pragma unroll
      for (int j = 0; j < 4; ++j)
        acc[i][j] = __builtin_amdgcn_mfma_f32_16x16x32_bf16(af[i], bfr[j], acc[i][j], 0, 0, 0);
    __syncthreads();
  }
#pragma unroll
  for (int i = 0; i < 4; ++i){
#pragma unroll
    for (int j = 0; j < 4; ++j){
      int row0 = bm*128 + wm*64 + i*16 + g*4;
      int col  = bn*128 + wn*64 + j*16 + col16;
#pragma unroll
      for (int r = 0; r < 4; ++r){
        float a = acc[i][j][r];
        if (MODE == 0){
          float t = a * 0.002f;
          t = t + bias[col];
          t = clip127(rintf(t));
          ((short*)Y)[(size_t)(row0 + r)*N + col] = f2bf(t);
        } else {
          float t = a * 0.001f;
          t = t + bias[col];
          ((float*)Y)[(size_t)(row0 + r)*N + col] = t;
        }
      }
    }
  }
}

// ---------------- RoPE (in place on q8 / k8) ----------------------------------
__global__ void rope_qk(short* __restrict__ q, short* __restrict__ k,
                        const float* __restrict__ cosp, const float* __restrict__ sinp){
#pragma clang fp contract(off)
  int idx = blockIdx.x * blockDim.x + threadIdx.x;
  int d = idx & (HALF-1);
  int h = (idx >> 6) & (NH-1);
  int s = idx >> 10;
  if (s >= S) return;
  float c = cosp[s*HALF + d], sn = sinp[s*HALF + d];
  int base = s*HID + h*HD + d;
  {
    float x0 = bf2f(q[base]) * 0.05f;
    float x1 = bf2f(q[base + HALF]) * 0.05f;
    float r0 = x0*c - x1*sn;
    float r1 = x0*sn + x1*c;
    q[base]        = f2bf(clip127(rintf(r0 / 0.06f)));
    q[base + HALF] = f2bf(clip127(rintf(r1 / 0.06f)));
  }
  {
    float x0 = bf2f(k[base]) * 0.05f;
    float x1 = bf2f(k[base + HALF]) * 0.05f;
    float r0 = x0*c - x1*sn;
    float r1 = x0*sn + x1*c;
    k[base]        = f2bf(clip127(rintf(r0 / 0.06f)));
    k[base + HALF] = f2bf(clip127(rintf(r1 / 0.06f)));
  }
}

// ---------------- V transpose: vt[h][d][s] = v[s][h*HD+d] ---------------------
__global__ void vtrans(const short* __restrict__ v, short* __restrict__ vt){
  __shared__ __attribute__((aligned(16))) short t[64][72];
  int s0 = blockIdx.x * 64, d0 = blockIdx.y * 64, h = blockIdx.z;
  int tid = threadIdx.x;
#pragma unroll
  for (int i = 0; i < 2; ++i){
    int vi = i*256 + tid;
    int r = vi >> 3, c = (vi & 7) * 8;
    *(bf16x8*)&t[r][c] = *(const bf16x8*)&v[(size_t)(s0 + r)*HID + h*HD + d0 + c];
  }
  __syncthreads();
#pragma unroll
  for (int i = 0; i < 2; ++i){
    int vi = i*256 + tid;
    int rd = vi >> 3, cs = (vi & 7) * 8;
    bf16x8 o;
#pragma unroll
    for (int j = 0; j < 8; ++j) o[j] = t[cs + j][rd];
    *(bf16x8*)&vt[(size_t)(h*HD + d0 + rd)*S + s0 + cs] = o;
  }
}

// ---------------- swizzled 128x128 bf16 LDS staging ---------------------------
__device__ __forceinline__ void stage_swz(short* dst, const short* src){
  const int tid = threadIdx.x;
#pragma unroll
  for (int i = 0; i < 8; ++i){
    int v = i*256 + tid;
    int row = v >> 4, chunk = v & 15;
    bf16x8 val = *(const bf16x8*)&src[(size_t)row*2048 + chunk*8];
    *(bf16x8*)((char*)dst + row*256 + ((chunk ^ (row & 7))*16)) = val;
  }
}
__device__ __forceinline__ bf16x8 rdfrag(const short* buf, int row, int chunk){
  return *(const bf16x8*)((const char*)buf + row*256 + ((chunk ^ (row & 7))*16));
}

// ---------------- S: per-(head, qt, kt) tile stats (balanced grid) -------------
__global__ __launch_bounds__(256)
void attn_stats(const short* __restrict__ qr, const short* __restrict__ kr,
                float2* __restrict__ stats){
  const int x = blockIdx.x, h = blockIdx.y;
  int qt = (int)((sqrtf(8.f*x + 1.f) - 1.f)*0.5f);
  while ((qt+1)*(qt+2)/2 <= x) ++qt;
  while (qt*(qt+1)/2 > x) --qt;
  const int kt = x - qt*(qt+1)/2;
  const int q0 = qt*128;
  const int tid = threadIdx.x, wid = tid >> 6, lane = tid & 63;
  const int col16 = lane & 15, g = lane >> 4;
  __shared__ __attribute__((aligned(16))) short Ks[128*128];

  bf16x8 aq[2][4];
#pragma unroll
  for (int i = 0; i < 2; ++i)
#pragma unroll
    for (int kk = 0; kk < 4; ++kk){
      int row = q0 + wid*32 + i*16 + col16;
      aq[i][kk] = *(const bf16x8*)&qr[(size_t)row*HID + h*HD + kk*32 + g*8];
    }
  stage_swz(Ks, kr + (size_t)(kt*128)*HID + h*HD);
  __syncthreads();

  f32x4 sc[2][8] = {};
#pragma unroll
  for (int kk = 0; kk < 4; ++kk){
    bf16x8 bk[8];
#pragma unroll
    for (int j = 0; j < 8; ++j) bk[j] = rdfrag(Ks, j*16 + col16, kk*4 + g);
#pragma unroll
    for (int i = 0; i < 2; ++i)
#pragma unroll
      for (int j = 0; j < 8; ++j)
        sc[i][j] = __builtin_amdgcn_mfma_f32_16x16x32_bf16(aq[i][kk], bk[j], sc[i][j], 0, 0, 0);
  }

  const bool diag = (kt == qt);
#pragma unroll
  for (int i = 0; i < 2; ++i){
#pragma unroll
    for (int r = 0; r < 4; ++r){
      int rit = wid*32 + i*16 + g*4 + r;
      int qrow = q0 + rit;
      float vals[8]; float mt = -3.0e38f;
#pragma unroll
      for (int j = 0; j < 8; ++j){
        float sv = sc[i][j][r] * SCORE_SCALE;
        if (diag && (kt*128 + j*16 + col16 > qrow)) sv = -1e9f;
        vals[j] = sv;
        mt = fmaxf(mt, sv);
      }
      mt = fmaxf(mt, __shfl_xor(mt, 1));
      mt = fmaxf(mt, __shfl_xor(mt, 2));
      mt = fmaxf(mt, __shfl_xor(mt, 4));
      mt = fmaxf(mt, __shfl_xor(mt, 8));
      float st = 0.f;
#pragma unroll
      for (int j = 0; j < 8; ++j) st += __expf(vals[j] - mt);
      st += __shfl_xor(st, 1);
      st += __shfl_xor(st, 2);
      st += __shfl_xor(st, 4);
      st += __shfl_xor(st, 8);
      if (col16 == 0) stats[(size_t)(h*136 + x)*128 + rit] = make_float2(mt, st);
    }
  }
}

// ---------------- R: combine tile stats -> final (m, l) per row ---------------
__global__ void attn_reduce(const float2* __restrict__ stats, float2* __restrict__ ml){
  const int row = threadIdx.x, qt = blockIdx.x, h = blockIdx.y;
  const int tri = qt*(qt+1)/2;
  float m = -3.0e38f;
  for (int kt = 0; kt <= qt; ++kt)
    m = fmaxf(m, stats[(size_t)(h*136 + tri + kt)*128 + row].x);
  float l = 0.f;
  for (int kt = 0; kt <= qt; ++kt){
    float2 s = stats[(size_t)(h*136 + tri + kt)*128 + row];
    l += s.y * __expf(s.x - m);
  }
  ml[(h*16 + qt)*128 + row] = make_float2(m, l);
}

// ---------------- P: balanced tile-parallel PV, exact fp32 atomic accum --------
// block x of 72 handles (qt, kt in {2c, 2c+1}):  C(2a)=a(a+1), C(2a+1)=(a+1)^2
__global__ __launch_bounds__(256, 2)
void attn_pv_tile(const short* __restrict__ qr, const short* __restrict__ kr,
                  const short* __restrict__ vt, const float2* __restrict__ ml,
                  float* __restrict__ Oacc){
  const int x = blockIdx.x, h = blockIdx.y;
  int a = (int)sqrtf((float)x);
  while ((a+1)*(a+1) <= x) ++a;
  while (a*a > x) --a;
  const int qt = (x >= a*(a+1)) ? 2*a : 2*a - 1;
  const int C  = (qt & 1) ? ((qt+1)/2)*((qt+1)/2) : (qt/2)*(qt/2 + 1);
  const int kt0 = (x - C) * 2;
  const int kt1 = min(kt0 + 1, qt);
  const int q0 = qt*128;
  const int tid = threadIdx.x, wid = tid >> 6, lane = tid & 63;
  const int col16 = lane & 15, g = lane >> 4;
  __shared__ __attribute__((aligned(16))) short Ks[128*128];   // K, then reused as P
  __shared__ __attribute__((aligned(16))) short Vs[128*128];

  bf16x8 aq[2][4];
#pragma unroll
  for (int i = 0; i < 2; ++i)
#pragma unroll
    for (int kk = 0; kk < 4; ++kk){
      int row = q0 + wid*32 + i*16 + col16;
      aq[i][kk] = *(const bf16x8*)&qr[(size_t)row*HID + h*HD + kk*32 + g*8];
    }
  float m[8], c[8];
#pragma unroll
  for (int i = 0; i < 2; ++i)
#pragma unroll
    for (int r = 0; r < 4; ++r){
      float2 t = ml[(h*16 + qt)*128 + wid*32 + i*16 + g*4 + r];
      m[i*4+r] = t.x;
      c[i*4+r] = 127.0f / t.y;
    }

  f32x4 ao[2][8] = {};
  for (int kt = kt0; kt <= kt1; ++kt){
    stage_swz(Ks, kr + (size_t)(kt*128)*HID + h*HD);
    __syncthreads();
    f32x4 sc[2][8] = {};
#pragma unroll
    for (int kk = 0; kk < 4; ++kk){
      bf16x8 bk[8];
#pragma unroll
      for (int j = 0; j < 8; ++j) bk[j] = rdfrag(Ks, j*16 + col16, kk*4 + g);
#pragma unroll
      for (int i = 0; i < 2; ++i)
#pragma unroll
        for (int j = 0; j < 8; ++j)
          sc[i][j] = __builtin_amdgcn_mfma_f32_16x16x32_bf16(aq[i][kk], bk[j], sc[i][j], 0, 0, 0);
    }
    __syncthreads();                       // all QK^T ds_reads of Ks retired
    stage_swz(Vs, vt + (size_t)(h*HD)*S + kt*128);   // V loads overlap p8 VALU
    const bool diag = (kt == qt);
#pragma unroll
    for (int i = 0; i < 2; ++i){
#pragma unroll
      for (int r = 0; r < 4; ++r){
        int idx = i*4 + r;
        int row = wid*32 + i*16 + g*4 + r;
        int qrow = q0 + row;
#pragma unroll
        for (int j = 0; j < 8; ++j){
          int colk = j*16 + col16;
          float p8v = 0.0f;
          if (!diag || (kt*128 + colk) <= qrow){
            float sv = sc[i][j][r] * SCORE_SCALE;
            p8v = clip127(rintf(__expf(sv - m[idx]) * c[idx]));
          }
          int chunk = colk >> 3;
          *(short*)((char*)Ks + row*256 + ((chunk ^ (row & 7))*16) + (colk & 7)*2) = f2bf(p8v);
        }
      }
    }
    __syncthreads();                       // P and V ready
#pragma unroll
    for (int kk = 0; kk < 4; ++kk){
      bf16x8 ap[2], bv[8];
#pragma unroll
      for (int i = 0; i < 2; ++i)
        ap[i] = rdfrag(Ks, wid*32 + i*16 + col16, kk*4 + g);
#pragma unroll
      for (int j = 0; j < 8; ++j)
        bv[j] = rdfrag(Vs, j*16 + col16, kk*4 + g);
#pragma unroll
      for (int i = 0; i < 2; ++i)
#pragma unroll
        for (int j = 0; j < 8; ++j)
          ao[i][j] = __builtin_amdgcn_mfma_f32_16x16x32_bf16(ap[i], bv[j], ao[i][j], 0, 0, 0);
    }
    __syncthreads();                       // tile consumed before restage
  }

  // exact integer fp32 atomic accumulation (deterministic)
#pragma unroll
  for (int i = 0; i < 2; ++i)
#pragma unroll
    for (int j = 0; j < 8; ++j)
#pragma unroll
      for (int r = 0; r < 4; ++r){
        int row = q0 + wid*32 + i*16 + g*4 + r;
        int d = j*16 + col16;
        atomicAdd(&Oacc[(size_t)row*HID + h*HD + d], ao[i][j][r]);
      }
}

// ---------------- quantize O accumulator -> o8 (bf16) -------------------------
__global__ void quant_o(const float* __restrict__ Oacc, short* __restrict__ o8, int n){
  int i = (blockIdx.x * blockDim.x + threadIdx.x) * 4;
  if (i >= n) return;
  float4 v = *(const float4*)(Oacc + i);
  float x[4] = {v.x, v.y, v.z, v.w};
  short4v o;
#pragma unroll
  for (int j = 0; j < 4; ++j) o[j] = f2bf(clip127(rintf(x[j] * OSCALE)));
  *(short4v*)(o8 + i) = o;
}

// ---------------- launch -------------------------------------------------------
extern "C" void kernel_launch(void* const* d_in, const int* in_sizes, int n_in,
                              void* d_out, int out_size, void* d_ws, size_t ws_size,
                              hipStream_t stream) {
  const float* hidden = (const float*)d_in[0];
  const float* cosp   = (const float*)d_in[1];
  const float* sinp   = (const float*)d_in[2];
  const float* wq     = (const float*)d_in[3];
  const float* wk     = (const float*)d_in[4];
  const float* wv     = (const float*)d_in[5];
  const float* wo     = (const float*)d_in[6];
  const float* bq     = (const float*)d_in[7];
  const float* bk     = (const float*)d_in[8];
  const float* bv     = (const float*)d_in[9];
  const float* bo     = (const float*)d_in[10];
  float* out = (float*)d_out;

  const size_t MAT = (size_t)HID * HID;
  short* ws  = (short*)d_ws;
  // slot layout (8.39MB each): Oacc reuses dead wvb+vb (adjacent slots 3,4)
  short* xbf = ws + 0*MAT;    // x8; reused as o8b after QKV GEMMs
  short* wqb = ws + 1*MAT;    // -> stats after gemmQ
  short* wkb = ws + 2*MAT;    // -> ml after gemmK
  short* wvb = ws + 3*MAT;    // dead after gemmV
  short* vb  = ws + 4*MAT;    // dead after vtrans
  short* wob = ws + 5*MAT;
  short* qb  = ws + 6*MAT;
  short* kb  = ws + 7*MAT;
  short* vtb = ws + 8*MAT;
  short* o8b = xbf;
  float2* stats = (float2*)wqb;           // 2.23 MB
  float2* mlb   = (float2*)wkb;           // 0.26 MB
  float*  Oacc  = (float*)(ws + 3*MAT);   // 16.78 MB, slots 3-4

  const int n = (int)MAT;
  dim3 b256(256);

  cvt_all<<<dim3(n/1024, 5), b256, 0, stream>>>(hidden, wq, wk, wv, wo,
                                                xbf, wqb, wkb, wvb, wob, n);

  dim3 gg(16, 16);
  gemm_bt<0><<<gg, b256, 0, stream>>>(xbf, wqb, bq, qb);
  gemm_bt<0><<<gg, b256, 0, stream>>>(xbf, wkb, bk, kb);
  gemm_bt<0><<<gg, b256, 0, stream>>>(xbf, wvb, bv, vb);

  rope_qk<<<(S*NH*HALF)/256, b256, 0, stream>>>(qb, kb, cosp, sinp);
  vtrans<<<dim3(S/64, HD/64, NH), b256, 0, stream>>>(vb, vtb);

  attn_stats<<<dim3(136, 16), b256, 0, stream>>>(qb, kb, stats);
  attn_reduce<<<dim3(16, 16), dim3(128), 0, stream>>>(stats, mlb);

  hipMemsetAsync(Oacc, 0, (size_t)S*HID*sizeof(float), stream);
  attn_pv_tile<<<dim3(72, 16), b256, 0, stream>>>(qb, kb, vtb, mlb, Oacc);
  quant_o<<<n/1024, b256, 0, stream>>>(Oacc, o8b, n);

  gemm_bt<1><<<gg, b256, 0, stream>>>(o8b, wob, bo, (void*)out);
}

// Round 4
// 182.326 us; speedup vs baseline: 2.4166x; 2.4166x over previous
//
#include <hip/hip_runtime.h>
#include <math.h>

typedef __attribute__((ext_vector_type(4))) int i32x4;
typedef signed char s8;

constexpr int S   = 2048;
constexpr int HID = 2048;
constexpr int NH  = 16;
constexpr int HD  = 128;
constexpr int HALF = 64;

#define SCORE_SCALE ((float)(0.06 * 0.06 * 0.08838834764831845))   // Q_ROT*K_ROT*INV_SQRT_HD
#define OSCALE      ((float)(((1.0 / 127.0) * 0.04) / 0.03))        // PROB*V_OUT/OUT_IN

__device__ __forceinline__ float clip127(float r){
  return fminf(fmaxf(r, -127.0f), 127.0f);
}
__device__ __forceinline__ i32x4 mfma_i8(i32x4 a, i32x4 b, i32x4 c){
  return __builtin_amdgcn_mfma_i32_16x16x64_i8(a, b, c, 0, 0, 0);
}

// ---- swizzled 128x128 int8 tile staging (16KB, 256 threads) ------------------
// byte = row*128 + ((ch ^ (row&7))*16): conflict-free writes and ~2-way reads
__device__ __forceinline__ void stage_i8(s8* dst, const s8* src, int stride){
  const int tid = threadIdx.x;
#pragma unroll
  for (int i = 0; i < 4; ++i){
    int v = i*256 + tid, row = v >> 3, ch = v & 7;
    i32x4 val = *(const i32x4*)(src + (size_t)row*stride + ch*16);
    *(i32x4*)(dst + row*128 + ((ch ^ (row & 7))*16)) = val;
  }
}
__device__ __forceinline__ i32x4 rd16(const s8* buf, int row, int ch){
  return *(const i32x4*)(buf + row*128 + ((ch ^ (row & 7))*16));
}

// ---------------- prep: one dispatch converts x (quant) + 4 weights -> int8 ----
__global__ void cvt_all(const float* __restrict__ hid, const float* __restrict__ wq,
                        const float* __restrict__ wk, const float* __restrict__ wv,
                        const float* __restrict__ wo, s8* __restrict__ xd,
                        s8* __restrict__ qd, s8* __restrict__ kd,
                        s8* __restrict__ vd, s8* __restrict__ od, int n){
  const float* srcs[5] = {hid, wq, wk, wv, wo};
  s8* dsts[5] = {xd, qd, kd, vd, od};
  int which = blockIdx.y;
  const float* src = srcs[which];
  s8* dst = dsts[which];
  int i = (blockIdx.x * blockDim.x + threadIdx.x) * 4;
  if (i >= n) return;
  float4 v = *(const float4*)(src + i);
  float x[4] = {v.x, v.y, v.z, v.w};
  unsigned packed = 0;
#pragma unroll
  for (int j = 0; j < 4; ++j){
    int b;
    if (which == 0) b = (int)clip127(rintf(x[j] / 0.02f));
    else            b = (int)x[j];                 // weights are exact small ints
    packed |= ((unsigned)(b & 255)) << (8*j);
  }
  *(unsigned*)(dst + i) = packed;
}

// ---------------- GEMM int8: Y = A(MxK) * Bt(NxK)^T, i32 accum (exact) ---------
// MODE 0: Y(int8) = clip(rint(acc*0.002 + bias[col]))
// MODE 1: Y(f32)  = acc*0.001 + bias[col]
template<int MODE>
__global__ __launch_bounds__(256)
void gemm_i8(const s8* __restrict__ A, const s8* __restrict__ Bt,
             const float* __restrict__ bias, void* __restrict__ Y){
#pragma clang fp contract(off)
  constexpr int Kd = 2048, N = 2048;
  __shared__ __attribute__((aligned(16))) s8 As[2][128*128];
  __shared__ __attribute__((aligned(16))) s8 Bs[2][128*128];
  const int bm = blockIdx.x, bn = blockIdx.y, tid = threadIdx.x;
  const int wid = tid >> 6, lane = tid & 63;
  const int wm = wid >> 1, wn = wid & 1;
  const int col16 = lane & 15, g = lane >> 4;
  i32x4 acc[4][4] = {};
  const s8* Ab = A + (size_t)(bm*128)*Kd;
  const s8* Bb = Bt + (size_t)(bn*128)*Kd;
  stage_i8(As[0], Ab, Kd);
  stage_i8(Bs[0], Bb, Kd);
  for (int kt = 0; kt < 16; ++kt){
    __syncthreads();
    if (kt < 15){
      stage_i8(As[(kt+1)&1], Ab + (kt+1)*128, Kd);
      stage_i8(Bs[(kt+1)&1], Bb + (kt+1)*128, Kd);
    }
    const s8* as = As[kt&1]; const s8* bs = Bs[kt&1];
#pragma unroll
    for (int kk = 0; kk < 2; ++kk){
      i32x4 af[4], bf[4];
#pragma unroll
      for (int i = 0; i < 4; ++i) af[i] = rd16(as, wm*64 + i*16 + col16, kk*4 + g);
#pragma unroll
      for (int j = 0; j < 4; ++j) bf[j] = rd16(bs, wn*64 + j*16 + col16, kk*4 + g);
#pragma unroll
      for (int i = 0; i < 4; ++i)
#pragma unroll
        for (int j = 0; j < 4; ++j)
          acc[i][j] = mfma_i8(af[i], bf[j], acc[i][j]);
    }
  }
#pragma unroll
  for (int i = 0; i < 4; ++i){
#pragma unroll
    for (int j = 0; j < 4; ++j){
      int row0 = bm*128 + wm*64 + i*16 + g*4;
      int col  = bn*128 + wn*64 + j*16 + col16;
#pragma unroll
      for (int r = 0; r < 4; ++r){
        float a = (float)acc[i][j][r];
        if (MODE == 0){
          float t = a * 0.002f;
          t = t + bias[col];
          ((s8*)Y)[(size_t)(row0 + r)*N + col] = (s8)(int)clip127(rintf(t));
        } else {
          float t = a * 0.001f;
          t = t + bias[col];
          ((float*)Y)[(size_t)(row0 + r)*N + col] = t;
        }
      }
    }
  }
}

// ---------------- RoPE (in place on int8 q/k) ----------------------------------
__global__ void rope_qk(s8* __restrict__ q, s8* __restrict__ k,
                        const float* __restrict__ cosp, const float* __restrict__ sinp){
#pragma clang fp contract(off)
  int idx = blockIdx.x * blockDim.x + threadIdx.x;   // S*NH*16 threads
  int t4 = (idx & 15) * 4;
  int h  = (idx >> 4) & (NH-1);
  int s  = idx >> 8;
  if (s >= S) return;
  float4 c4 = *(const float4*)(cosp + s*HALF + t4);
  float4 s4 = *(const float4*)(sinp + s*HALF + t4);
  float cc[4] = {c4.x, c4.y, c4.z, c4.w}, ss[4] = {s4.x, s4.y, s4.z, s4.w};
  int base = s*HID + h*HD + t4;
  {
    int a0 = *(const int*)(q + base), a1 = *(const int*)(q + base + HALF);
    unsigned o0 = 0, o1 = 0;
#pragma unroll
    for (int j = 0; j < 4; ++j){
      float x0 = (float)((s8)(a0 >> (8*j))) * 0.05f;
      float x1 = (float)((s8)(a1 >> (8*j))) * 0.05f;
      float r0 = x0*cc[j] - x1*ss[j];
      float r1 = x0*ss[j] + x1*cc[j];
      o0 |= ((unsigned)(((int)clip127(rintf(r0 / 0.06f))) & 255)) << (8*j);
      o1 |= ((unsigned)(((int)clip127(rintf(r1 / 0.06f))) & 255)) << (8*j);
    }
    *(unsigned*)(q + base) = o0; *(unsigned*)(q + base + HALF) = o1;
  }
  {
    int a0 = *(const int*)(k + base), a1 = *(const int*)(k + base + HALF);
    unsigned o0 = 0, o1 = 0;
#pragma unroll
    for (int j = 0; j < 4; ++j){
      float x0 = (float)((s8)(a0 >> (8*j))) * 0.05f;
      float x1 = (float)((s8)(a1 >> (8*j))) * 0.05f;
      float r0 = x0*cc[j] - x1*ss[j];
      float r1 = x0*ss[j] + x1*cc[j];
      o0 |= ((unsigned)(((int)clip127(rintf(r0 / 0.06f))) & 255)) << (8*j);
      o1 |= ((unsigned)(((int)clip127(rintf(r1 / 0.06f))) & 255)) << (8*j);
    }
    *(unsigned*)(k + base) = o0; *(unsigned*)(k + base + HALF) = o1;
  }
}

// ---------------- V transpose (int8): vt[h][d][s] = v[s][h*HD+d] ---------------
__global__ void vtrans(const s8* __restrict__ v, s8* __restrict__ vt){
  __shared__ __attribute__((aligned(16))) s8 t[128*144];
  int s0 = blockIdx.x * 128, h = blockIdx.y;
  int tid = threadIdx.x;
#pragma unroll
  for (int i = 0; i < 4; ++i){
    int vv = i*256 + tid, r = vv >> 3, ch = vv & 7;
    *(i32x4*)(t + r*144 + ch*16) = *(const i32x4*)(v + (size_t)(s0 + r)*HID + h*HD + ch*16);
  }
  __syncthreads();
#pragma unroll
  for (int i = 0; i < 4; ++i){
    int vv = i*256 + tid, d = vv >> 3, sc = (vv & 7)*16;
    s8 tmp[16];
#pragma unroll
    for (int j = 0; j < 16; ++j) tmp[j] = t[(sc + j)*144 + d];
    *(i32x4*)(vt + (size_t)(h*HD + d)*S + s0 + sc) = *(i32x4*)tmp;
  }
}

// ---------------- S: per-(head, tri-tile) stats --------------------------------
__global__ __launch_bounds__(256)
void attn_stats(const s8* __restrict__ qr, const s8* __restrict__ kr,
                float2* __restrict__ stats){
  const int x = blockIdx.x, h = blockIdx.y;
  int qt = (int)((sqrtf(8.f*x + 1.f) - 1.f)*0.5f);
  while ((qt+1)*(qt+2)/2 <= x) ++qt;
  while (qt*(qt+1)/2 > x) --qt;
  const int kt = x - qt*(qt+1)/2;
  const int q0 = qt*128;
  const int tid = threadIdx.x, wid = tid >> 6, lane = tid & 63;
  const int col16 = lane & 15, g = lane >> 4;
  __shared__ __attribute__((aligned(16))) s8 Ks[128*128];

  i32x4 aq[2][2];
#pragma unroll
  for (int i = 0; i < 2; ++i)
#pragma unroll
    for (int kk = 0; kk < 2; ++kk)
      aq[i][kk] = *(const i32x4*)(qr + (size_t)(q0 + wid*32 + i*16 + col16)*HID + h*HD + kk*64 + g*16);
  stage_i8(Ks, kr + (size_t)(kt*128)*HID + h*HD, HID);
  __syncthreads();

  i32x4 sc[2][8] = {};
#pragma unroll
  for (int kk = 0; kk < 2; ++kk){
    i32x4 bk[8];
#pragma unroll
    for (int j = 0; j < 8; ++j) bk[j] = rd16(Ks, j*16 + col16, kk*4 + g);
#pragma unroll
    for (int i = 0; i < 2; ++i)
#pragma unroll
      for (int j = 0; j < 8; ++j)
        sc[i][j] = mfma_i8(aq[i][kk], bk[j], sc[i][j]);
  }

  const bool diag = (kt == qt);
#pragma unroll
  for (int i = 0; i < 2; ++i){
#pragma unroll
    for (int r = 0; r < 4; ++r){
      int rit = wid*32 + i*16 + g*4 + r;
      int qrow = q0 + rit;
      float vals[8]; float mt = -3.0e38f;
#pragma unroll
      for (int j = 0; j < 8; ++j){
        float sv = (float)sc[i][j][r] * SCORE_SCALE;
        if (diag && (kt*128 + j*16 + col16 > qrow)) sv = -1e9f;
        vals[j] = sv;
        mt = fmaxf(mt, sv);
      }
      mt = fmaxf(mt, __shfl_xor(mt, 1));
      mt = fmaxf(mt, __shfl_xor(mt, 2));
      mt = fmaxf(mt, __shfl_xor(mt, 4));
      mt = fmaxf(mt, __shfl_xor(mt, 8));
      float st = 0.f;
#pragma unroll
      for (int j = 0; j < 8; ++j) st += __expf(vals[j] - mt);
      st += __shfl_xor(st, 1);
      st += __shfl_xor(st, 2);
      st += __shfl_xor(st, 4);
      st += __shfl_xor(st, 8);
      if (col16 == 0) stats[(size_t)(h*136 + x)*128 + rit] = make_float2(mt, st);
    }
  }
}

// ---------------- R: combine tile stats -> final (m, l) per row ----------------
__global__ void attn_reduce(const float2* __restrict__ stats, float2* __restrict__ ml){
  const int row = threadIdx.x, qt = blockIdx.x, h = blockIdx.y;
  const int tri = qt*(qt+1)/2;
  float m = -3.0e38f;
  for (int kt = 0; kt <= qt; ++kt)
    m = fmaxf(m, stats[(size_t)(h*136 + tri + kt)*128 + row].x);
  float l = 0.f;
  for (int kt = 0; kt <= qt; ++kt){
    float2 s = stats[(size_t)(h*136 + tri + kt)*128 + row];
    l += s.y * __expf(s.x - m);
  }
  ml[(h*16 + qt)*128 + row] = make_float2(m, l);
}

// ---------------- Q: per-(head, tri-tile) p8 tile -> global int8 P -------------
__global__ __launch_bounds__(256)
void attn_score(const s8* __restrict__ qr, const s8* __restrict__ kr,
                const float2* __restrict__ ml, s8* __restrict__ P8){
  const int x = blockIdx.x, h = blockIdx.y;
  int qt = (int)((sqrtf(8.f*x + 1.f) - 1.f)*0.5f);
  while ((qt+1)*(qt+2)/2 <= x) ++qt;
  while (qt*(qt+1)/2 > x) --qt;
  const int kt = x - qt*(qt+1)/2;
  const int q0 = qt*128;
  const int tid = threadIdx.x, wid = tid >> 6, lane = tid & 63;
  const int col16 = lane & 15, g = lane >> 4;
  __shared__ __attribute__((aligned(16))) s8 Ks[128*128];

  i32x4 aq[2][2];
#pragma unroll
  for (int i = 0; i < 2; ++i)
#pragma unroll
    for (int kk = 0; kk < 2; ++kk)
      aq[i][kk] = *(const i32x4*)(qr + (size_t)(q0 + wid*32 + i*16 + col16)*HID + h*HD + kk*64 + g*16);
  float m[8], c[8];
#pragma unroll
  for (int i = 0; i < 2; ++i)
#pragma unroll
    for (int r = 0; r < 4; ++r){
      float2 t = ml[(h*16 + qt)*128 + wid*32 + i*16 + g*4 + r];
      m[i*4+r] = t.x;
      c[i*4+r] = 127.0f / t.y;
    }
  stage_i8(Ks, kr + (size_t)(kt*128)*HID + h*HD, HID);
  __syncthreads();

  i32x4 sc[2][8] = {};
#pragma unroll
  for (int kk = 0; kk < 2; ++kk){
    i32x4 bk[8];
#pragma unroll
    for (int j = 0; j < 8; ++j) bk[j] = rd16(Ks, j*16 + col16, kk*4 + g);
#pragma unroll
    for (int i = 0; i < 2; ++i)
#pragma unroll
      for (int j = 0; j < 8; ++j)
        sc[i][j] = mfma_i8(aq[i][kk], bk[j], sc[i][j]);
  }
  __syncthreads();                   // Ks reads retired; reuse as P tile
  s8* Pl = Ks;
  const bool diag = (kt == qt);
#pragma unroll
  for (int i = 0; i < 2; ++i){
#pragma unroll
    for (int r = 0; r < 4; ++r){
      int idx = i*4 + r;
      int row = wid*32 + i*16 + g*4 + r;
      int qrow = q0 + row;
#pragma unroll
      for (int j = 0; j < 8; ++j){
        int colk = j*16 + col16;
        float p8v = 0.0f;
        if (!diag || (kt*128 + colk) <= qrow){
          float sv = (float)sc[i][j][r] * SCORE_SCALE;
          p8v = clip127(rintf(__expf(sv - m[idx]) * c[idx]));
        }
        Pl[row*128 + colk] = (s8)(int)p8v;
      }
    }
  }
  __syncthreads();
  s8* dst = P8 + (size_t)(h*136 + x)*16384;
#pragma unroll
  for (int i = 0; i < 4; ++i){
    int v = i*256 + tid, row = v >> 3, ch = v & 7;
    *(i32x4*)(dst + row*128 + ch*16) = *(const i32x4*)(Pl + row*128 + ch*16);
  }
}

// ---------------- P: PV as a pure int8 GEMM over kt (double-buffered) ----------
__global__ __launch_bounds__(256)
void attn_pv(const s8* __restrict__ P8, const s8* __restrict__ vt8,
             s8* __restrict__ o8){
  const int qt = blockIdx.x, h = blockIdx.y;
  const int tri = qt*(qt+1)/2;
  const int tid = threadIdx.x, wid = tid >> 6, lane = tid & 63;
  const int col16 = lane & 15, g = lane >> 4;
  __shared__ __attribute__((aligned(16))) s8 Ps[2][128*128];
  __shared__ __attribute__((aligned(16))) s8 Vs[2][128*128];

  i32x4 ao[2][8] = {};
  stage_i8(Ps[0], P8 + (size_t)(h*136 + tri)*16384, 128);
  stage_i8(Vs[0], vt8 + (size_t)(h*HD)*S, S);
  for (int kt = 0; kt <= qt; ++kt){
    __syncthreads();
    if (kt < qt){
      stage_i8(Ps[(kt+1)&1], P8 + (size_t)(h*136 + tri + kt + 1)*16384, 128);
      stage_i8(Vs[(kt+1)&1], vt8 + (size_t)(h*HD)*S + (kt+1)*128, S);
    }
    const s8* ps = Ps[kt&1]; const s8* vs = Vs[kt&1];
#pragma unroll
    for (int kk = 0; kk < 2; ++kk){
      i32x4 ap[2], bv[8];
#pragma unroll
      for (int i = 0; i < 2; ++i) ap[i] = rd16(ps, wid*32 + i*16 + col16, kk*4 + g);
#pragma unroll
      for (int j = 0; j < 8; ++j) bv[j] = rd16(vs, j*16 + col16, kk*4 + g);
#pragma unroll
      for (int i = 0; i < 2; ++i)
#pragma unroll
        for (int j = 0; j < 8; ++j)
          ao[i][j] = mfma_i8(ap[i], bv[j], ao[i][j]);
    }
  }
#pragma unroll
  for (int i = 0; i < 2; ++i)
#pragma unroll
    for (int j = 0; j < 8; ++j)
#pragma unroll
      for (int r = 0; r < 4; ++r){
        int row = qt*128 + wid*32 + i*16 + g*4 + r;
        int d = j*16 + col16;
        o8[(size_t)row*HID + h*HD + d] = (s8)(int)clip127(rintf((float)ao[i][j][r] * OSCALE));
      }
}

// ---------------- launch --------------------------------------------------------
extern "C" void kernel_launch(void* const* d_in, const int* in_sizes, int n_in,
                              void* d_out, int out_size, void* d_ws, size_t ws_size,
                              hipStream_t stream) {
  const float* hidden = (const float*)d_in[0];
  const float* cosp   = (const float*)d_in[1];
  const float* sinp   = (const float*)d_in[2];
  const float* wq     = (const float*)d_in[3];
  const float* wk     = (const float*)d_in[4];
  const float* wv     = (const float*)d_in[5];
  const float* wo     = (const float*)d_in[6];
  const float* bq     = (const float*)d_in[7];
  const float* bk     = (const float*)d_in[8];
  const float* bv     = (const float*)d_in[9];
  const float* bo     = (const float*)d_in[10];
  float* out = (float*)d_out;

  const size_t MB = 1024*1024;
  s8* ws8 = (s8*)d_ws;
  s8* x8  = ws8 + 0*MB;     // 4MB; reused as o8 (x8 dead after QKV GEMMs)
  s8* wq8 = ws8 + 4*MB;     // dead after gemm Q -> stats/ml overlay
  s8* wk8 = ws8 + 8*MB;
  s8* wv8 = ws8 + 12*MB;
  s8* wo8 = ws8 + 16*MB;
  s8* q8  = ws8 + 20*MB;
  s8* k8  = ws8 + 24*MB;
  s8* v8  = ws8 + 28*MB;
  s8* vt8 = ws8 + 32*MB;
  s8* P8  = ws8 + 36*MB;    // 16*136*16384 = 35.65MB -> ends ~71.7MB
  s8* o8  = x8;
  float2* stats = (float2*)(ws8 + 4*MB);                 // 2.23MB
  float2* mlb   = (float2*)(ws8 + 4*MB + 2400*1024);     // 0.26MB

  const int n = HID*HID;
  dim3 b256(256);

  cvt_all<<<dim3(n/1024, 5), b256, 0, stream>>>(hidden, wq, wk, wv, wo,
                                                x8, wq8, wk8, wv8, wo8, n);

  dim3 gg(16, 16);
  gemm_i8<0><<<gg, b256, 0, stream>>>(x8, wq8, bq, q8);
  gemm_i8<0><<<gg, b256, 0, stream>>>(x8, wk8, bk, k8);
  gemm_i8<0><<<gg, b256, 0, stream>>>(x8, wv8, bv, v8);

  rope_qk<<<(S*NH*16)/256, b256, 0, stream>>>(q8, k8, cosp, sinp);
  vtrans<<<dim3(S/128, NH), b256, 0, stream>>>(v8, vt8);

  attn_stats<<<dim3(136, 16), b256, 0, stream>>>(q8, k8, stats);
  attn_reduce<<<dim3(16, 16), dim3(128), 0, stream>>>(stats, mlb);
  attn_score<<<dim3(136, 16), b256, 0, stream>>>(q8, k8, mlb, P8);
  attn_pv<<<gg, b256, 0, stream>>>(P8, vt8, o8);

  gemm_i8<1><<<gg, b256, 0, stream>>>(o8, wo8, bo, (void*)out);
}